// Round 2
// baseline (273.364 us; speedup 1.0000x reference)
//
#include <hip/hip_runtime.h>

#define LOG2E 1.44269504088896340736f

typedef __bf16 bf16_t;
typedef bf16_t bf16x8 __attribute__((ext_vector_type(8)));
typedef bf16_t bf16x4 __attribute__((ext_vector_type(4)));
typedef float f32x4 __attribute__((ext_vector_type(4)));

// Problem constants: N=4096 nodes, F_in=512, F_out=128, H=8 heads.

// ---- K0a: pack adjacency (int32 0/1, 64MB) into bitmask (2MB) ----
__global__ __launch_bounds__(256) void k_pack_adj(const int* __restrict__ adj,
                                                  unsigned long long* __restrict__ mask64) {
  const int lane = threadIdx.x & 63;
  const int wave = ((blockIdx.x << 8) + threadIdx.x) >> 6;
  const int nwave = gridDim.x << 2;
  for (int word = wave; word < 4096 * 64; word += nwave) {
    const int v = adj[(size_t)word * 64 + lane];
    const unsigned long long m = __ballot(v > 0);
    if (lane == 0) mask64[word] = m;
  }
}

// ---- K0b: x fp32 -> bf16 ----
__global__ __launch_bounds__(256) void k_cvt_x(const float* __restrict__ x,
                                               bf16_t* __restrict__ xb) {
  const int t = blockIdx.x * 256 + threadIdx.x;  // 262144 threads, 8 elems each
  const f32x4 a = ((const f32x4*)x)[t * 2];
  const f32x4 b = ((const f32x4*)x)[t * 2 + 1];
  bf16x8 o;
#pragma unroll
  for (int i = 0; i < 4; ++i) { o[i] = (bf16_t)a[i]; o[i + 4] = (bf16_t)b[i]; }
  ((bf16x8*)xb)[t] = o;
}

// ---- K0c: W [h][k][o] fp32 -> WT [h][o][k] bf16 (transpose for MFMA B-frags) ----
__global__ __launch_bounds__(256) void k_cvt_w(const float* __restrict__ W,
                                               bf16_t* __restrict__ WT) {
  const int t = blockIdx.x * 256 + threadIdx.x;  // 524288
  const int k = t & 511, o = (t >> 9) & 127, h = t >> 16;
  WT[t] = (bf16_t)W[((h << 9) + k) * 128 + o];
}

// ---- K1: Wh = x@W per head; store WhT[h][o][n] bf16; fuse f_src/f_dst epilogue ----
// block = 4 waves, tile M=64 (16 rows/wave), N=128 (full F_out), K=512.
__global__ __launch_bounds__(256) void k_gemm_wh(const bf16_t* __restrict__ xb,
                                                 const bf16_t* __restrict__ WT,
                                                 const float* __restrict__ a_src,
                                                 const float* __restrict__ a_dst,
                                                 bf16_t* __restrict__ WhT,
                                                 float* __restrict__ f_src,
                                                 float* __restrict__ f_dst) {
  const int h = blockIdx.y;
  const int n0 = blockIdx.x * 64;
  const int lane = threadIdx.x & 63;
  const int w = threadIdx.x >> 6;
  const int col = lane & 15;  // A-row selector / D-col selector
  const int kg = lane >> 4;   // k-chunk selector
  const bf16_t* xrow = xb + (size_t)(n0 + w * 16 + col) * 512 + kg * 8;
  const bf16_t* wb = WT + ((size_t)h << 16) + (size_t)col * 512 + kg * 8;
  f32x4 acc[8] = {};
  for (int kk = 0; kk < 512; kk += 32) {
    const bf16x8 a = *(const bf16x8*)(xrow + kk);
#pragma unroll
    for (int ot = 0; ot < 8; ++ot) {
      const bf16x8 b = *(const bf16x8*)(wb + ot * (16 * 512) + kk);
      acc[ot] = __builtin_amdgcn_mfma_f32_16x16x32_bf16(a, b, acc[ot], 0, 0, 0);
    }
  }
  // f_src/f_dst: dot each Wh row (fp32 acc) with a_src/a_dst, reduce across the
  // 16 lanes that share a row group (o-dimension lives on lane&15).
  float ps[4] = {0.f, 0.f, 0.f, 0.f}, pd[4] = {0.f, 0.f, 0.f, 0.f};
#pragma unroll
  for (int ot = 0; ot < 8; ++ot) {
    const float as = a_src[h * 128 + ot * 16 + col];
    const float ad = a_dst[h * 128 + ot * 16 + col];
#pragma unroll
    for (int r = 0; r < 4; ++r) { ps[r] += acc[ot][r] * as; pd[r] += acc[ot][r] * ad; }
  }
#pragma unroll
  for (int m = 1; m < 16; m <<= 1) {
#pragma unroll
    for (int r = 0; r < 4; ++r) {
      ps[r] += __shfl_xor(ps[r], m, 64);
      pd[r] += __shfl_xor(pd[r], m, 64);
    }
  }
  const int nb = n0 + w * 16 + kg * 4;
  if (col == 0) {
#pragma unroll
    for (int r = 0; r < 4; ++r) {
      f_src[h * 4096 + nb + r] = ps[r] * LOG2E;  // pre-scale: exp(x)=exp2(x*log2e)
      f_dst[h * 4096 + nb + r] = pd[r] * LOG2E;
    }
  }
  // store WhT[h][o][n] (D frag: row m=(l>>4)*4+r -> n, col=l&15 -> o)
#pragma unroll
  for (int ot = 0; ot < 8; ++ot) {
    bf16x4 v;
#pragma unroll
    for (int r = 0; r < 4; ++r) v[r] = (bf16_t)acc[ot][r];
    *(bf16x4*)(WhT + ((size_t)(h * 128 + ot * 16 + col) << 12) + nb) = v;
  }
}

// ---- K3: flash-style masked softmax + PV ----
// grid (32 i-tiles, 8 heads); block 512 thr = 8 waves: 4 row-groups (32 rows each)
// x 2 j-halves. P built directly in MFMA A-fragment layout; no max-subtraction
// needed (logits bounded ~|6|). acc merged across j-halves via LDS.
__global__ __launch_bounds__(512, 2) void k_pv(const bf16_t* __restrict__ WhT,
                                               const float* __restrict__ f_src,
                                               const float* __restrict__ f_dst,
                                               const unsigned char* __restrict__ mask,
                                               float* __restrict__ out) {
  __shared__ float lds_acc[4][32][128];
  __shared__ float lds_den[8][32];
  const int h = blockIdx.y;
  const int i0 = blockIdx.x * 128;
  const int lane = threadIdx.x & 63;
  const int w = threadIdx.x >> 6;
  const int wr = w & 3, wj = w >> 2;
  const int col = lane & 15, kg = lane >> 4;
  const int rbase = i0 + wr * 32;
  const float sv0 = f_src[h * 4096 + rbase + col];
  const float sv1 = f_src[h * 4096 + rbase + 16 + col];
  const unsigned char* m0 = mask + (size_t)(rbase + col) * 512 + kg;
  const unsigned char* m1 = mask + (size_t)(rbase + 16 + col) * 512 + kg;
  const float* fd = f_dst + h * 4096 + kg * 8;
  const bf16_t* wh = WhT + ((size_t)h << 19) + ((size_t)col << 12) + kg * 8;
  f32x4 acc0[8] = {};
  f32x4 acc1[8] = {};
  float den0 = 0.f, den1 = 0.f;
  for (int it = 0; it < 64; ++it) {
    const int j0 = (it * 2 + wj) * 32;
    const f32x4 dlo = *(const f32x4*)(fd + j0);
    const f32x4 dhi = *(const f32x4*)(fd + j0 + 4);
    const unsigned mb0 = m0[j0 >> 3];
    const unsigned mb1 = m1[j0 >> 3];
    bf16x8 a0, a1;
#pragma unroll
    for (int e = 0; e < 8; ++e) {
      const float dv = (e < 4) ? dlo[e] : dhi[e - 4];
      float t0 = sv0 + dv;
      t0 = fmaxf(t0, 0.2f * t0);  // LeakyReLU (scale commutes with max)
      const float p0 = ((mb0 >> e) & 1) ? __builtin_amdgcn_exp2f(t0) : 0.0f;
      float t1 = sv1 + dv;
      t1 = fmaxf(t1, 0.2f * t1);
      const float p1 = ((mb1 >> e) & 1) ? __builtin_amdgcn_exp2f(t1) : 0.0f;
      a0[e] = (bf16_t)p0;
      a1[e] = (bf16_t)p1;
      den0 += p0;
      den1 += p1;
    }
    const bf16_t* whj = wh + j0;
#pragma unroll
    for (int ot = 0; ot < 8; ++ot) {
      const bf16x8 b = *(const bf16x8*)(whj + ot * (16 * 4096));
      acc0[ot] = __builtin_amdgcn_mfma_f32_16x16x32_bf16(a0, b, acc0[ot], 0, 0, 0);
      acc1[ot] = __builtin_amdgcn_mfma_f32_16x16x32_bf16(a1, b, acc1[ot], 0, 0, 0);
    }
  }
  // denominator: sum over the 4 k-chunk lane groups (lanes sharing col)
  den0 += __shfl_xor(den0, 16, 64);
  den0 += __shfl_xor(den0, 32, 64);
  den1 += __shfl_xor(den1, 16, 64);
  den1 += __shfl_xor(den1, 32, 64);
  if (lane < 16) {
    lds_den[w][lane] = den0;
    lds_den[w][16 + lane] = den1;
  }
  if (wj == 1) {
#pragma unroll
    for (int ot = 0; ot < 8; ++ot) {
#pragma unroll
      for (int r = 0; r < 4; ++r) {
        lds_acc[wr][kg * 4 + r][ot * 16 + col] = acc0[ot][r];
        lds_acc[wr][16 + kg * 4 + r][ot * 16 + col] = acc1[ot][r];
      }
    }
  }
  __syncthreads();
  if (wj == 0) {
#pragma unroll
    for (int s = 0; s < 2; ++s) {
#pragma unroll
      for (int r = 0; r < 4; ++r) {
        const int row = s * 16 + kg * 4 + r;
        const float dsum = lds_den[wr][row] + lds_den[wr + 4][row];
        const float inv = __builtin_amdgcn_rcpf(dsum);
        float* op = out + (size_t)(rbase + row) * 1024 + h * 128;
#pragma unroll
        for (int ot = 0; ot < 8; ++ot) {
          const float v = (s == 0 ? acc0[ot][r] : acc1[ot][r]) + lds_acc[wr][row][ot * 16 + col];
          op[ot * 16 + col] = v * inv;
        }
      }
    }
  }
}

extern "C" void kernel_launch(void* const* d_in, const int* in_sizes, int n_in,
                              void* d_out, int out_size, void* d_ws, size_t ws_size,
                              hipStream_t stream) {
  const float* x = (const float*)d_in[0];
  const int* adj = (const int*)d_in[1];
  const float* W = (const float*)d_in[2];
  const float* a_src = (const float*)d_in[3];
  const float* a_dst = (const float*)d_in[4];
  float* out = (float*)d_out;
  char* ws = (char*)d_ws;
  // workspace layout (bytes):
  //   WhT   [8][128][4096] bf16 : 0        .. 8388608
  //   xb    [4096][512]   bf16 : 8388608  .. 12582912
  //   WT    [8][128][512]  bf16 : 12582912 .. 13631488   (1 MB = 524288 elems * 2B!)
  //   mask  [4096][512]    u8   : 13631488 .. 15728640
  //   f_src [8][4096]      f32  : 15728640 .. 15859712
  //   f_dst [8][4096]      f32  : 15859712 .. 15990784
  bf16_t* WhT = (bf16_t*)(ws);
  bf16_t* xb = (bf16_t*)(ws + 8388608);
  bf16_t* WT = (bf16_t*)(ws + 12582912);
  unsigned long long* mask64 = (unsigned long long*)(ws + 13631488);
  float* f_src = (float*)(ws + 15728640);
  float* f_dst = (float*)(ws + 15859712);

  k_pack_adj<<<1024, 256, 0, stream>>>(adj, mask64);
  k_cvt_x<<<1024, 256, 0, stream>>>(x, xb);
  k_cvt_w<<<2048, 256, 0, stream>>>(W, WT);
  k_gemm_wh<<<dim3(64, 8), 256, 0, stream>>>(xb, WT, a_src, a_dst, WhT, f_src, f_dst);
  k_pv<<<dim3(32, 8), 512, 0, stream>>>(WhT, f_src, f_dst, (const unsigned char*)mask64, out);
}

// Round 3
// 188.908 us; speedup vs baseline: 1.4471x; 1.4471x over previous
//
#include <hip/hip_runtime.h>

#define LOG2E 1.44269504088896340736f

typedef __bf16 bf16_t;
typedef bf16_t bf16x8 __attribute__((ext_vector_type(8)));
typedef bf16_t bf16x4 __attribute__((ext_vector_type(4)));
typedef float f32x4 __attribute__((ext_vector_type(4)));

// Problem constants: N=4096 nodes, F_in=512, F_out=128, H=8 heads.

// ---- K0a: pack adjacency (int32 0/1, 64MB) into bitmask (2MB) ----
__global__ __launch_bounds__(256) void k_pack_adj(const int* __restrict__ adj,
                                                  unsigned long long* __restrict__ mask64) {
  const int lane = threadIdx.x & 63;
  const int wave = ((blockIdx.x << 8) + threadIdx.x) >> 6;
  const int nwave = gridDim.x << 2;
  for (int word = wave; word < 4096 * 64; word += nwave) {
    const int v = adj[(size_t)word * 64 + lane];
    const unsigned long long m = __ballot(v > 0);
    if (lane == 0) mask64[word] = m;
  }
}

// ---- K0b: x fp32 -> bf16 ----
__global__ __launch_bounds__(256) void k_cvt_x(const float* __restrict__ x,
                                               bf16_t* __restrict__ xb) {
  const int t = blockIdx.x * 256 + threadIdx.x;
  const f32x4 a = ((const f32x4*)x)[t * 2];
  const f32x4 b = ((const f32x4*)x)[t * 2 + 1];
  bf16x8 o;
#pragma unroll
  for (int i = 0; i < 4; ++i) { o[i] = (bf16_t)a[i]; o[i + 4] = (bf16_t)b[i]; }
  ((bf16x8*)xb)[t] = o;
}

// ---- K0c: W [h][k][o] fp32 -> WT [h][o][k] bf16 ----
__global__ __launch_bounds__(256) void k_cvt_w(const float* __restrict__ W,
                                               bf16_t* __restrict__ WT) {
  const int t = blockIdx.x * 256 + threadIdx.x;  // 524288
  const int k = t & 511, o = (t >> 9) & 127, h = t >> 16;
  WT[t] = (bf16_t)W[((h << 9) + k) * 128 + o];
}

// ---- K1: Wh = x@W per head. Store WhB pre-swizzled in PV B-fragment order:
// element (h, o, j) -> WhB[ ((h*128 + j/32)*8 + o/16)*512 + ((j>>3)&3)*128 + (o&15)*8 + (j&7) ]
// so k_pv's per-(jb,ot) bf16x8 load is lane-contiguous (1KB coalesced).
// Also fuses f_src/f_dst epilogue.
__global__ __launch_bounds__(256) void k_gemm_wh(const bf16_t* __restrict__ xb,
                                                 const bf16_t* __restrict__ WT,
                                                 const float* __restrict__ a_src,
                                                 const float* __restrict__ a_dst,
                                                 bf16_t* __restrict__ WhB,
                                                 float* __restrict__ f_src,
                                                 float* __restrict__ f_dst) {
  const int h = blockIdx.y;
  const int n0 = blockIdx.x * 64;
  const int lane = threadIdx.x & 63;
  const int w = threadIdx.x >> 6;
  const int col = lane & 15;
  const int kg = lane >> 4;
  const bf16_t* xrow = xb + (size_t)(n0 + w * 16 + col) * 512 + kg * 8;
  const bf16_t* wb = WT + ((size_t)h << 16) + (size_t)col * 512 + kg * 8;
  f32x4 acc[8] = {};
  for (int kk = 0; kk < 512; kk += 32) {
    const bf16x8 a = *(const bf16x8*)(xrow + kk);
#pragma unroll
    for (int ot = 0; ot < 8; ++ot) {
      const bf16x8 b = *(const bf16x8*)(wb + ot * (16 * 512) + kk);
      acc[ot] = __builtin_amdgcn_mfma_f32_16x16x32_bf16(a, b, acc[ot], 0, 0, 0);
    }
  }
  // f_src/f_dst epilogue (o lives on lane&15; reduce over 16 lanes)
  float ps[4] = {0.f, 0.f, 0.f, 0.f}, pd[4] = {0.f, 0.f, 0.f, 0.f};
#pragma unroll
  for (int ot = 0; ot < 8; ++ot) {
    const float as = a_src[h * 128 + ot * 16 + col];
    const float ad = a_dst[h * 128 + ot * 16 + col];
#pragma unroll
    for (int r = 0; r < 4; ++r) { ps[r] += acc[ot][r] * as; pd[r] += acc[ot][r] * ad; }
  }
#pragma unroll
  for (int m = 1; m < 16; m <<= 1) {
#pragma unroll
    for (int r = 0; r < 4; ++r) {
      ps[r] += __shfl_xor(ps[r], m, 64);
      pd[r] += __shfl_xor(pd[r], m, 64);
    }
  }
  const int nb = n0 + w * 16 + kg * 4;  // j-index of acc[.][0]
  if (col == 0) {
#pragma unroll
    for (int r = 0; r < 4; ++r) {
      f_src[h * 4096 + nb + r] = ps[r] * LOG2E;  // pre-scale: exp(x)=exp2(x*log2e)
      f_dst[h * 4096 + nb + r] = pd[r] * LOG2E;
    }
  }
  // swizzled store: j = nb..nb+3 share jb, kg_t, e0 (nb is 4-aligned)
  const int jb = nb >> 5;
  const int kgt = (nb >> 3) & 3;
  const int e0 = nb & 4;
  const size_t base = ((size_t)(h * 128 + jb) * 8) * 512 + kgt * 128 + col * 8 + e0;
#pragma unroll
  for (int ot = 0; ot < 8; ++ot) {
    bf16x4 v;
#pragma unroll
    for (int r = 0; r < 4; ++r) v[r] = (bf16_t)acc[ot][r];
    *(bf16x4*)(WhB + base + ot * 512) = v;
  }
}

// ---- K2: masked softmax-numerator + PV partials over a j-slice ----
// grid = 32 i-tiles x 8 heads x S slices (flattened, head-per-XCD swizzle);
// block = 4 waves, each wave 32 rows, all waves share the j-slice B stream.
// No LDS. den computed via MFMA with ones-B. Partials to num_ws/den_ws.
__global__ __launch_bounds__(256, 4) void k_pv(const bf16_t* __restrict__ WhB,
                                               const float* __restrict__ f_src,
                                               const float* __restrict__ f_dst,
                                               const unsigned char* __restrict__ mask,
                                               float* __restrict__ num_ws,
                                               float* __restrict__ den_ws,
                                               int jper) {
  const int bx = blockIdx.x;
  const int h = bx & 7;          // head -> XCD (round-robin dispatch heuristic)
  const int i0 = ((bx >> 3) & 31) * 128;
  const int s = bx >> 8;
  const int lane = threadIdx.x & 63;
  const int wr = threadIdx.x >> 6;
  const int col = lane & 15, kg = lane >> 4;
  const int rbase = i0 + wr * 32;
  const int jbeg = s * jper;
  const int iters = jper >> 5;
  const float sv0 = f_src[h * 4096 + rbase + col];
  const float sv1 = f_src[h * 4096 + rbase + 16 + col];
  const unsigned char* m0 = mask + (size_t)(rbase + col) * 512 + kg + (jbeg >> 3);
  const unsigned char* m1 = m0 + 16 * 512;
  const float* fd = f_dst + h * 4096 + jbeg + kg * 8;
  const bf16_t* whB = WhB + ((size_t)h << 19) + (size_t)(jbeg >> 5) * 4096 + lane * 8;
  f32x4 acc0[8] = {}, acc1[8] = {};
  f32x4 den0 = {}, den1 = {};
  bf16x8 ones;
#pragma unroll
  for (int e = 0; e < 8; ++e) ones[e] = (bf16_t)1.0f;
  for (int it = 0; it < iters; ++it) {
    const f32x4 dlo = *(const f32x4*)(fd + it * 32);
    const f32x4 dhi = *(const f32x4*)(fd + it * 32 + 4);
    const unsigned mb0 = m0[it * 4];
    const unsigned mb1 = m1[it * 4];
    bf16x8 a0, a1;
#pragma unroll
    for (int e = 0; e < 8; ++e) {
      const float dv = (e < 4) ? dlo[e] : dhi[e - 4];
      float t0 = sv0 + dv;
      t0 = fmaxf(t0, 0.2f * t0);  // LeakyReLU (log2e scale commutes with max)
      const float p0 = __builtin_amdgcn_exp2f(t0) * (float)((mb0 >> e) & 1);
      float t1 = sv1 + dv;
      t1 = fmaxf(t1, 0.2f * t1);
      const float p1 = __builtin_amdgcn_exp2f(t1) * (float)((mb1 >> e) & 1);
      a0[e] = (bf16_t)p0;
      a1[e] = (bf16_t)p1;
    }
    den0 = __builtin_amdgcn_mfma_f32_16x16x32_bf16(a0, ones, den0, 0, 0, 0);
    den1 = __builtin_amdgcn_mfma_f32_16x16x32_bf16(a1, ones, den1, 0, 0, 0);
    const bf16_t* wp = whB + (size_t)it * 4096;
#pragma unroll
    for (int ot = 0; ot < 8; ++ot) {
      const bf16x8 b = *(const bf16x8*)(wp + ot * 512);
      acc0[ot] = __builtin_amdgcn_mfma_f32_16x16x32_bf16(a0, b, acc0[ot], 0, 0, 0);
      acc1[ot] = __builtin_amdgcn_mfma_f32_16x16x32_bf16(a1, b, acc1[ot], 0, 0, 0);
    }
  }
  // store partials: D frag row m = kg*4+r, col n = col
  float* np = num_ws + ((size_t)((s * 8 + h) * 4096) + rbase) * 128;
#pragma unroll
  for (int ot = 0; ot < 8; ++ot) {
#pragma unroll
    for (int r = 0; r < 4; ++r) {
      np[(kg * 4 + r) * 128 + ot * 16 + col] = acc0[ot][r];
      np[(16 + kg * 4 + r) * 128 + ot * 16 + col] = acc1[ot][r];
    }
  }
  if (col == 0) {
    float* dp = den_ws + (size_t)(s * 8 + h) * 4096 + rbase;
#pragma unroll
    for (int r = 0; r < 4; ++r) {
      dp[kg * 4 + r] = den0[r];
      dp[16 + kg * 4 + r] = den1[r];
    }
  }
}

// ---- K3: merge slices + normalize -> out[n][h*128+o] ----
__global__ __launch_bounds__(256) void k_merge(const float* __restrict__ num_ws,
                                               const float* __restrict__ den_ws,
                                               float* __restrict__ out, int nslice) {
  const int g = blockIdx.x * 256 + threadIdx.x;  // 1M threads x 4 floats
  const int g4 = g * 4;
  const int o = g4 & 127, h = (g4 >> 7) & 7, n = g4 >> 10;
  f32x4 sum = {};
  float d = 0.f;
  for (int sl = 0; sl < nslice; ++sl) {
    sum += *(const f32x4*)(num_ws + ((size_t)((sl * 8 + h) * 4096) + n) * 128 + o);
    d += den_ws[(size_t)(sl * 8 + h) * 4096 + n];
  }
  const float inv = __builtin_amdgcn_rcpf(d);
  f32x4 r;
#pragma unroll
  for (int i = 0; i < 4; ++i) r[i] = sum[i] * inv;
  *(f32x4*)(out + g4) = r;
}

extern "C" void kernel_launch(void* const* d_in, const int* in_sizes, int n_in,
                              void* d_out, int out_size, void* d_ws, size_t ws_size,
                              hipStream_t stream) {
  const float* x = (const float*)d_in[0];
  const int* adj = (const int*)d_in[1];
  const float* W = (const float*)d_in[2];
  const float* a_src = (const float*)d_in[3];
  const float* a_dst = (const float*)d_in[4];
  float* out = (float*)d_out;
  char* ws = (char*)d_ws;
  // workspace layout (bytes):
  //   WhB   swizzled bf16        : 0        .. 8388608
  //   xb    [4096][512] bf16     : 8388608  .. 12582912
  //   WT    [8][128][512] bf16   : 12582912 .. 13631488
  //   mask  [4096][512] u8       : 13631488 .. 15728640
  //   f_src [8][4096] f32        : 15728640 .. 15859712
  //   f_dst [8][4096] f32        : 15859712 .. 15990784
  //   den_ws [S][8][4096] f32    : 15990784 .. +S*131072
  //   num_ws [S][8][4096][128]   : ..       .. +S*16777216
  const size_t FIXED = 15990784;
  int S = (ws_size >= FIXED + 4ull * (131072 + 16777216)) ? 4 : 1;
  bf16_t* WhB = (bf16_t*)(ws);
  bf16_t* xb = (bf16_t*)(ws + 8388608);
  bf16_t* WT = (bf16_t*)(ws + 12582912);
  unsigned long long* mask64 = (unsigned long long*)(ws + 13631488);
  float* f_src = (float*)(ws + 15728640);
  float* f_dst = (float*)(ws + 15859712);
  float* den_ws = (float*)(ws + FIXED);
  float* num_ws = (float*)(ws + FIXED + (size_t)S * 131072);

  k_pack_adj<<<1024, 256, 0, stream>>>(adj, mask64);
  k_cvt_x<<<1024, 256, 0, stream>>>(x, xb);
  k_cvt_w<<<2048, 256, 0, stream>>>(W, WT);
  k_gemm_wh<<<dim3(64, 8), 256, 0, stream>>>(xb, WT, a_src, a_dst, WhB, f_src, f_dst);
  k_pv<<<256 * S, 256, 0, stream>>>(WhB, f_src, f_dst, (const unsigned char*)mask64,
                                    num_ws, den_ws, 4096 / S);
  k_merge<<<4096, 256, 0, stream>>>(num_ws, den_ws, out, S);
}

// Round 4
// 141.411 us; speedup vs baseline: 1.9331x; 1.3359x over previous
//
#include <hip/hip_runtime.h>

#define LOG2E 1.44269504088896340736f

typedef _Float16 f16_t;
typedef f16_t f16x8 __attribute__((ext_vector_type(8)));
typedef f16_t f16x4 __attribute__((ext_vector_type(4)));
typedef float f32x4 __attribute__((ext_vector_type(4)));

// Problem constants: N=4096 nodes, F_in=512, F_out=128, H=8 heads.

// ---- K0a: pack adjacency (int32 0/1, 64MB) into bitmask (2MB) ----
// byte-per-thread: each thread reads 8 ints (2x int4), writes 1 mask byte.
__global__ __launch_bounds__(256) void k_pack_adj(const int* __restrict__ adj,
                                                  unsigned char* __restrict__ mask8) {
  const int t = blockIdx.x * 256 + threadIdx.x;  // 2M threads
  const int4 a = ((const int4*)adj)[t * 2];
  const int4 b = ((const int4*)adj)[t * 2 + 1];
  unsigned v = (a.x > 0) | ((a.y > 0) << 1) | ((a.z > 0) << 2) | ((a.w > 0) << 3) |
               ((b.x > 0) << 4) | ((b.y > 0) << 5) | ((b.z > 0) << 6) | ((b.w > 0) << 7);
  mask8[t] = (unsigned char)v;
}

// ---- K0b: x fp32 -> fp16 ----
__global__ __launch_bounds__(256) void k_cvt_x(const float* __restrict__ x,
                                               f16_t* __restrict__ xh) {
  const int t = blockIdx.x * 256 + threadIdx.x;
  const f32x4 a = ((const f32x4*)x)[t * 2];
  const f32x4 b = ((const f32x4*)x)[t * 2 + 1];
  f16x8 o;
#pragma unroll
  for (int i = 0; i < 4; ++i) { o[i] = (f16_t)a[i]; o[i + 4] = (f16_t)b[i]; }
  ((f16x8*)xh)[t] = o;
}

// ---- K0c: W [h][k][o] fp32 -> WT [h][o][k] fp16 ----
__global__ __launch_bounds__(256) void k_cvt_w(const float* __restrict__ W,
                                               f16_t* __restrict__ WT) {
  const int t = blockIdx.x * 256 + threadIdx.x;  // 524288
  const int k = t & 511, o = (t >> 9) & 127, h = t >> 16;
  WT[t] = (f16_t)W[((h << 9) + k) * 128 + o];
}

// ---- K1: Wh = x@W per head (fp16 MFMA). Store WhB pre-swizzled in PV
// B-fragment order; epilogue computes the piecewise-exp tables
// EA=2^(fs*L), EA2=2^(0.2*fs*L), EB=2^(fd*L), EB2=2^(0.2*fd*L) as fp16.
__global__ __launch_bounds__(256) void k_gemm_wh(const f16_t* __restrict__ xh,
                                                 const f16_t* __restrict__ WT,
                                                 const float* __restrict__ a_src,
                                                 const float* __restrict__ a_dst,
                                                 f16_t* __restrict__ WhB,
                                                 f16_t* __restrict__ EA,
                                                 f16_t* __restrict__ EA2,
                                                 f16_t* __restrict__ EB,
                                                 f16_t* __restrict__ EB2) {
  const int h = blockIdx.y;
  const int n0 = blockIdx.x * 64;
  const int lane = threadIdx.x & 63;
  const int w = threadIdx.x >> 6;
  const int col = lane & 15;
  const int kg = lane >> 4;
  const f16_t* xrow = xh + (size_t)(n0 + w * 16 + col) * 512 + kg * 8;
  const f16_t* wb = WT + ((size_t)h << 16) + (size_t)col * 512 + kg * 8;
  f32x4 acc[8] = {};
  for (int kk = 0; kk < 512; kk += 32) {
    const f16x8 a = *(const f16x8*)(xrow + kk);
#pragma unroll
    for (int ot = 0; ot < 8; ++ot) {
      const f16x8 b = *(const f16x8*)(wb + ot * (16 * 512) + kk);
      acc[ot] = __builtin_amdgcn_mfma_f32_16x16x32_f16(a, b, acc[ot], 0, 0, 0);
    }
  }
  // f_src/f_dst epilogue (o lives on lane&15; reduce over 16 lanes)
  float ps[4] = {0.f, 0.f, 0.f, 0.f}, pd[4] = {0.f, 0.f, 0.f, 0.f};
#pragma unroll
  for (int ot = 0; ot < 8; ++ot) {
    const float as = a_src[h * 128 + ot * 16 + col];
    const float ad = a_dst[h * 128 + ot * 16 + col];
#pragma unroll
    for (int r = 0; r < 4; ++r) { ps[r] += acc[ot][r] * as; pd[r] += acc[ot][r] * ad; }
  }
#pragma unroll
  for (int m = 1; m < 16; m <<= 1) {
#pragma unroll
    for (int r = 0; r < 4; ++r) {
      ps[r] += __shfl_xor(ps[r], m, 64);
      pd[r] += __shfl_xor(pd[r], m, 64);
    }
  }
  const int nb = n0 + w * 16 + kg * 4;  // node index of acc[.][0]
  if (col == 0) {
#pragma unroll
    for (int r = 0; r < 4; ++r) {
      const float fs = ps[r] * LOG2E;
      const float fd = pd[r] * LOG2E;
      const int idx = h * 4096 + nb + r;
      EA[idx] = (f16_t)__builtin_amdgcn_exp2f(fs);
      EA2[idx] = (f16_t)__builtin_amdgcn_exp2f(0.2f * fs);
      EB[idx] = (f16_t)__builtin_amdgcn_exp2f(fd);
      EB2[idx] = (f16_t)__builtin_amdgcn_exp2f(0.2f * fd);
    }
  }
  // swizzled store: element (h,o,j) -> WhB[((h*128+j/32)*8+o/16)*512 + ((j>>3)&3)*128 + (o&15)*8 + (j&7)]
  const int jb = nb >> 5;
  const int kgt = (nb >> 3) & 3;
  const int e0 = nb & 4;
  const size_t base = ((size_t)(h * 128 + jb) * 8) * 512 + kgt * 128 + col * 8 + e0;
#pragma unroll
  for (int ot = 0; ot < 8; ++ot) {
    f16x4 v;
#pragma unroll
    for (int r = 0; r < 4; ++r) v[r] = (f16_t)acc[ot][r];
    *(f16x4*)(WhB + base + ot * 512) = v;
  }
}

// ---- K2: masked softmax-numerator + PV partials over a j-slice ----
// p_ij = max(EA_i*EB_j, EA2_i*EB2_j) * m_ij  (piecewise exp of LeakyReLU:
// 2^t vs 2^{0.2t} — the larger one is the correct branch). All packed fp16.
// Mask byte -> 8 fp16 {0,1} via 256-entry LDS LUT. den via MFMA with ones-B.
__global__ __launch_bounds__(256, 4) void k_pv(const f16_t* __restrict__ WhB,
                                               const f16_t* __restrict__ EA,
                                               const f16_t* __restrict__ EA2,
                                               const f16_t* __restrict__ EB,
                                               const f16_t* __restrict__ EB2,
                                               const unsigned char* __restrict__ mask,
                                               f16_t* __restrict__ num_ws,
                                               float* __restrict__ den_ws,
                                               int jper) {
  __shared__ __align__(16) unsigned short lut[256][8];
  {
    const int t = threadIdx.x;
#pragma unroll
    for (int e = 0; e < 8; ++e) lut[t][e] = ((t >> e) & 1) ? 0x3C00 : 0;
  }
  __syncthreads();
  const int bx = blockIdx.x;
  const int h = bx & 7;  // head -> XCD round-robin
  const int i0 = ((bx >> 3) & 31) * 128;
  const int s = bx >> 8;
  const int lane = threadIdx.x & 63;
  const int wr = threadIdx.x >> 6;
  const int col = lane & 15, kg = lane >> 4;
  const int rbase = i0 + wr * 32;
  const int jbeg = s * jper;
  const int iters = jper >> 5;
  const int row0 = rbase + col, row1 = rbase + 16 + col;
  // per-row splats
  f16x8 A0s, A20s, A1s, A21s, ones;
  {
    const f16_t A0 = EA[h * 4096 + row0], A20 = EA2[h * 4096 + row0];
    const f16_t A1 = EA[h * 4096 + row1], A21 = EA2[h * 4096 + row1];
#pragma unroll
    for (int e = 0; e < 8; ++e) {
      A0s[e] = A0; A20s[e] = A20; A1s[e] = A1; A21s[e] = A21; ones[e] = (f16_t)1.0f;
    }
  }
  const unsigned char* m0 = mask + (size_t)row0 * 512 + kg + (jbeg >> 3);
  const unsigned char* m1 = mask + (size_t)row1 * 512 + kg + (jbeg >> 3);
  const f16_t* EBp = EB + h * 4096 + jbeg + kg * 8;
  const f16_t* EB2p = EB2 + h * 4096 + jbeg + kg * 8;
  const f16_t* whB = WhB + ((size_t)h << 19) + (size_t)(jbeg >> 5) * 4096 + lane * 8;
  f32x4 acc0[8] = {}, acc1[8] = {};
  f32x4 den0 = {}, den1 = {};
  for (int it = 0; it < iters; ++it) {
    const f16x8 vb = *(const f16x8*)(EBp + it * 32);
    const f16x8 vb2 = *(const f16x8*)(EB2p + it * 32);
    const unsigned mb0 = m0[it * 4];
    const unsigned mb1 = m1[it * 4];
    const f16x8 lm0 = *(const f16x8*)(&lut[mb0][0]);
    const f16x8 lm1 = *(const f16x8*)(&lut[mb1][0]);
    const f16x8 a0 = __builtin_elementwise_max(A0s * vb, A20s * vb2) * lm0;
    const f16x8 a1 = __builtin_elementwise_max(A1s * vb, A21s * vb2) * lm1;
    den0 = __builtin_amdgcn_mfma_f32_16x16x32_f16(a0, ones, den0, 0, 0, 0);
    den1 = __builtin_amdgcn_mfma_f32_16x16x32_f16(a1, ones, den1, 0, 0, 0);
    const f16_t* wp = whB + (size_t)it * 4096;
#pragma unroll
    for (int ot = 0; ot < 8; ++ot) {
      const f16x8 b = *(const f16x8*)(wp + ot * 512);
      acc0[ot] = __builtin_amdgcn_mfma_f32_16x16x32_f16(a0, b, acc0[ot], 0, 0, 0);
      acc1[ot] = __builtin_amdgcn_mfma_f32_16x16x32_f16(a1, b, acc1[ot], 0, 0, 0);
    }
  }
  // store partials (fp16 num, f32 den): D frag row m = kg*4+r, col n = col
  f16_t* np = num_ws + ((size_t)((s * 8 + h) * 4096) + rbase) * 128;
#pragma unroll
  for (int ot = 0; ot < 8; ++ot) {
#pragma unroll
    for (int r = 0; r < 4; ++r) {
      np[(kg * 4 + r) * 128 + ot * 16 + col] = (f16_t)acc0[ot][r];
      np[(16 + kg * 4 + r) * 128 + ot * 16 + col] = (f16_t)acc1[ot][r];
    }
  }
  if (col == 0) {
    float* dp = den_ws + (size_t)(s * 8 + h) * 4096 + rbase;
#pragma unroll
    for (int r = 0; r < 4; ++r) {
      dp[kg * 4 + r] = den0[r];
      dp[16 + kg * 4 + r] = den1[r];
    }
  }
}

// ---- K3: merge slices + normalize -> out[n][h*128+o] fp32 ----
__global__ __launch_bounds__(256) void k_merge(const f16_t* __restrict__ num_ws,
                                               const float* __restrict__ den_ws,
                                               float* __restrict__ out, int nslice) {
  const int g4 = (blockIdx.x * 256 + threadIdx.x) * 4;
  const int o = g4 & 127, h = (g4 >> 7) & 7, n = g4 >> 10;
  f32x4 sum = {};
  float d = 0.f;
  for (int sl = 0; sl < nslice; ++sl) {
    const f16x4 v = *(const f16x4*)(num_ws + ((size_t)((sl * 8 + h) * 4096) + n) * 128 + o);
#pragma unroll
    for (int i = 0; i < 4; ++i) sum[i] += (float)v[i];
    d += den_ws[(size_t)(sl * 8 + h) * 4096 + n];
  }
  const float inv = __builtin_amdgcn_rcpf(d);
  f32x4 r;
#pragma unroll
  for (int i = 0; i < 4; ++i) r[i] = sum[i] * inv;
  *(f32x4*)(out + g4) = r;
}

extern "C" void kernel_launch(void* const* d_in, const int* in_sizes, int n_in,
                              void* d_out, int out_size, void* d_ws, size_t ws_size,
                              hipStream_t stream) {
  const float* x = (const float*)d_in[0];
  const int* adj = (const int*)d_in[1];
  const float* W = (const float*)d_in[2];
  const float* a_src = (const float*)d_in[3];
  const float* a_dst = (const float*)d_in[4];
  float* out = (float*)d_out;
  char* ws = (char*)d_ws;
  // workspace layout (bytes):
  //   WhB   swizzled f16          : 0        .. 8388608
  //   xh    [4096][512] f16       : 8388608  .. 12582912
  //   WT    [8][128][512] f16     : 12582912 .. 13631488
  //   mask  [4096][512] u8        : 13631488 .. 15728640
  //   EA/EA2/EB/EB2 [8][4096] f16 : 15728640 .. 15990784 (4 x 64KB)
  //   den_ws [S][8][4096] f32     : 15990784 .. +S*131072
  //   num_ws [S][8][4096][128] f16: ..       .. +S*8388608
  const size_t FIXED = 15990784;
  int S = (ws_size >= FIXED + 4ull * (131072 + 8388608)) ? 4 : 1;
  f16_t* WhB = (f16_t*)(ws);
  f16_t* xh = (f16_t*)(ws + 8388608);
  f16_t* WT = (f16_t*)(ws + 12582912);
  unsigned char* mask8 = (unsigned char*)(ws + 13631488);
  f16_t* EA = (f16_t*)(ws + 15728640);
  f16_t* EA2 = (f16_t*)(ws + 15794176);
  f16_t* EB = (f16_t*)(ws + 15859712);
  f16_t* EB2 = (f16_t*)(ws + 15925248);
  float* den_ws = (float*)(ws + FIXED);
  f16_t* num_ws = (f16_t*)(ws + FIXED + (size_t)S * 131072);

  k_pack_adj<<<8192, 256, 0, stream>>>(adj, mask8);
  k_cvt_x<<<1024, 256, 0, stream>>>(x, xh);
  k_cvt_w<<<2048, 256, 0, stream>>>(W, WT);
  k_gemm_wh<<<dim3(64, 8), 256, 0, stream>>>(xh, WT, a_src, a_dst, WhB, EA, EA2, EB, EB2);
  k_pv<<<256 * S, 256, 0, stream>>>(WhB, EA, EA2, EB, EB2, mask8, num_ws, den_ws, 4096 / S);
  k_merge<<<4096, 256, 0, stream>>>(num_ws, den_ws, out, S);
}